// Round 5
// baseline (695.765 us; speedup 1.0000x reference)
//
#include <hip/hip_runtime.h>
#include <cstdint>
#include <cstddef>

// EncoderLayer: x(4,2048,1024) f32.
//   prep:  W* (KxN f32) -> W*T (NxK bf16); x f32 -> xb bf16
//   G1: qkv_b  = xb @ WqkvT + bqkv              (8192x3072, bf16 out)  BN=256
//   attn: per-position 16x16 head attention, out (N,H,S,hd) = scrambled reshape
//   G2: ao2    = aob @ WoT + bo                 (8192x1024, f32 out)   BN=128
//   LN1: h = LN(ao2 + x)  -> h_f (f32) + h_b (bf16)
//   G3: ff1_b  = relu(h_b @ W1T + bf1)          (8192x4096, bf16 out)  BN=256
//   G4: ff2    = ff1_b @ W2T + bf2   SPLIT-K=2  (8192x1024)            BN=256
//   LN2: out = LN(ff2 + p2 + h_f)               (f32 -> d_out)
//
// GEMM v3: 4-phase/K-tile with ONE-PHASE READ-AHEAD: each phase issues the
// ds_reads for the NEXT phase's MFMA quadrant, so LDS delivery overlaps the
// current MFMA cluster (compiler emits counted lgkmcnt). Staging slots are
// consumption-derived; counted vmcnt BEFORE each barrier gives CU-wide
// residency with 5-6 phase latency windows. b0 frags double-buffered via
// x2-unrolled loop (static register sets, rule #20).

using f32x4  = __attribute__((ext_vector_type(4))) float;
using bf16x8 = __attribute__((ext_vector_type(8))) __bf16;

__device__ __forceinline__ unsigned short f2b(float f) {
  union { float f; uint32_t u; } v; v.f = f;
  uint32_t r = v.u + 0x7FFFu + ((v.u >> 16) & 1u);  // RNE
  return (unsigned short)(r >> 16);
}
__device__ __forceinline__ float b2f(unsigned short u) {
  union { uint32_t u; float f; } v; v.u = ((uint32_t)u) << 16;
  return v.f;
}

__device__ __forceinline__ void gload_lds16(const unsigned short* g,
                                            unsigned short* l) {
  __builtin_amdgcn_global_load_lds(
      (const __attribute__((address_space(1))) unsigned int*)g,
      (__attribute__((address_space(3))) unsigned int*)l, 16, 0, 0);
}

#define MEMBAR() asm volatile("" ::: "memory")
__device__ __forceinline__ void barrier_raw() {
  MEMBAR();
  __builtin_amdgcn_s_barrier();
  MEMBAR();
}
template <int N>
__device__ __forceinline__ void vmwait() {
  static_assert(N >= 0 && N <= 12, "vmcnt range");
  if constexpr (N == 0)  asm volatile("s_waitcnt vmcnt(0)" ::: "memory");
  if constexpr (N == 1)  asm volatile("s_waitcnt vmcnt(1)" ::: "memory");
  if constexpr (N == 2)  asm volatile("s_waitcnt vmcnt(2)" ::: "memory");
  if constexpr (N == 3)  asm volatile("s_waitcnt vmcnt(3)" ::: "memory");
  if constexpr (N == 4)  asm volatile("s_waitcnt vmcnt(4)" ::: "memory");
  if constexpr (N == 5)  asm volatile("s_waitcnt vmcnt(5)" ::: "memory");
  if constexpr (N == 6)  asm volatile("s_waitcnt vmcnt(6)" ::: "memory");
  if constexpr (N == 7)  asm volatile("s_waitcnt vmcnt(7)" ::: "memory");
  if constexpr (N == 8)  asm volatile("s_waitcnt vmcnt(8)" ::: "memory");
  if constexpr (N == 9)  asm volatile("s_waitcnt vmcnt(9)" ::: "memory");
  if constexpr (N == 10) asm volatile("s_waitcnt vmcnt(10)" ::: "memory");
  if constexpr (N == 11) asm volatile("s_waitcnt vmcnt(11)" ::: "memory");
  if constexpr (N == 12) asm volatile("s_waitcnt vmcnt(12)" ::: "memory");
}

// ---------------- weight transpose + convert: W (KxN f32) -> WT (NxK bf16) ----
__global__ __launch_bounds__(256) void transpose_cvt_kernel(
    const float* __restrict__ W, unsigned short* __restrict__ WT, int K, int N) {
  __shared__ float tile[32][33];
  const int j0 = blockIdx.x * 32, k0 = blockIdx.y * 32;
  const int tx = threadIdx.x, ty = threadIdx.y;
#pragma unroll
  for (int i = 0; i < 4; ++i)
    tile[ty + 8 * i][tx] = W[(size_t)(k0 + ty + 8 * i) * N + j0 + tx];
  __syncthreads();
#pragma unroll
  for (int i = 0; i < 4; ++i)
    WT[(size_t)(j0 + ty + 8 * i) * K + k0 + tx] = f2b(tile[tx][ty + 8 * i]);
}

// ---------------- f32 -> bf16 elementwise ------------------------------------
__global__ __launch_bounds__(256) void cvt_bf16_kernel(
    const float* __restrict__ in, unsigned short* __restrict__ out, int n4) {
  for (int i = blockIdx.x * blockDim.x + threadIdx.x; i < n4;
       i += gridDim.x * blockDim.x) {
    float4 v = ((const float4*)in)[i];
    uint32_t lo = (uint32_t)f2b(v.x) | ((uint32_t)f2b(v.y) << 16);
    uint32_t hi = (uint32_t)f2b(v.z) | ((uint32_t)f2b(v.w) << 16);
    ((uint2*)out)[i] = make_uint2(lo, hi);
  }
}

// ---------------- GEMM: C(MxN) = A(MxK,bf16) * B^T(NxK,bf16) + bias ----------
template <int BN, bool SPLITK, bool OUTB, bool RELU>
__global__ __launch_bounds__(512, 2) void gemm8p_kernel(
    const unsigned short* __restrict__ A, const unsigned short* __restrict__ B,
    const float* __restrict__ bias, void* __restrict__ C,
    unsigned short* __restrict__ C2, int M, int N, int Ks, int Kd, int nbn) {
  constexpr int NF   = BN / 128;          // n-frags per quadrant per wave
  constexpr int WN   = BN / 8;            // wave col extent within a B-half
  constexpr int BH   = BN / 2;            // B half rows
  constexpr int SA   = 2;                 // gload issues per A-half
  constexpr int SB   = NF;                // gload issues per B-half
  constexpr int ASTR = (256 + BN) * 64;   // elements per dbuf
  // derived counted vmcnt values (see schedule derivation in comments)
  constexpr int W1  = 2 * SA + 2 * SB;    // end P1 -> guards P2 read Ah1(t)
  constexpr int W2  = 2 * SA + 3 * SB;    // end P2 -> guards P3 read Ah0(t+1)
  constexpr int W3  = 2 * SA + 3 * SB;    // end P3 -> guards P4 read Bh0(t+1)
  constexpr int W4  = 3 * SA + 2 * SB;    // end P4 -> guards P1 read Bh1(t+1)
  constexpr int W2a = SA + 2 * SB;        // tail (t = NT-2) variants
  constexpr int W3a = SA + SB;
  constexpr int W4a = SA;

  __shared__ unsigned short lds[2 * ASTR];  // 128 KB (BN=256) / 96 KB (BN=128)

  const int tid  = threadIdx.x;
  const int lane = tid & 63, wave = tid >> 6;
  const int wm = wave >> 2, wn = wave & 3;  // 2 x 4 wave grid
  const int lr = lane & 15, lk = lane >> 4;
  const int x7 = lr & 7;

  // XCD-chunked swizzle, bn-fastest (all grids % 8 == 0)
  const int nwg = gridDim.x, cpx = nwg >> 3, id = blockIdx.x;
  const int wg = (id & 7) * cpx + (id >> 3);
  int bm, bn, sk;
  if (SPLITK) { bm = wg >> 3; bn = (wg & 7) >> 1; sk = wg & 1; }
  else        { bm = wg / nbn; bn = wg % nbn; sk = 0; }

  const unsigned short* Ab = A + (size_t)bm * 256 * Ks + (size_t)sk * Kd;
  const unsigned short* Bb = B + (size_t)bn * BN * Ks + (size_t)sk * Kd;

  // staging: per issue, 512 lanes x 16B = 64 rows x 128B; source pre-swizzled
  const int srow = tid >> 3;                       // row within 64-row group
  const int scol = ((tid & 7) ^ (srow & 7)) * 8;   // swizzled col element
  const int ldst = wave * 8 * 64;                  // wave dest offset (elems)

  const int NT = Kd >> 6;  // even, >= 6

  f32x4 acc[8][2 * NF] = {};
  bf16x8 a0[4][2], a1[4][2], b0[NF][2], b0n[NF][2], b1[NF][2];

#define STA(T, H, BUF)                                                        \
  _Pragma("unroll") for (int i_ = 0; i_ < 2; ++i_)                            \
      gload_lds16(Ab + (size_t)((H)*128 + i_ * 64 + srow) * Ks + (T)*64 + scol,\
                  &lds[(BUF)*ASTR + ((H)*128 + i_ * 64) * 64 + ldst])
#define STB(T, H, BUF)                                                        \
  _Pragma("unroll") for (int i_ = 0; i_ < SB; ++i_)                           \
      gload_lds16(Bb + (size_t)((H)*BH + i_ * 64 + srow) * Ks + (T)*64 + scol, \
                  &lds[(BUF)*ASTR + 256 * 64 + ((H)*BH + i_ * 64) * 64 + ldst])
#define RDA(BUF, H, DST)                                                      \
  _Pragma("unroll") for (int mi_ = 0; mi_ < 4; ++mi_)                         \
    _Pragma("unroll") for (int kk_ = 0; kk_ < 2; ++kk_)                       \
      DST[mi_][kk_] = *(const bf16x8*)&lds[(BUF)*ASTR +                       \
          ((H)*128 + wm * 64 + mi_ * 16 + lr) * 64 + ((kk_ * 4 + lk) ^ x7) * 8]
#define RDB(BUF, H, DST)                                                      \
  _Pragma("unroll") for (int ni_ = 0; ni_ < NF; ++ni_)                        \
    _Pragma("unroll") for (int kk_ = 0; kk_ < 2; ++kk_)                       \
      DST[ni_][kk_] = *(const bf16x8*)&lds[(BUF)*ASTR + 256 * 64 +            \
          ((H)*BH + wn * WN + ni_ * 16 + lr) * 64 + ((kk_ * 4 + lk) ^ x7) * 8]
#define MMQ(AS, BS, MH, NH)                                                   \
  do {                                                                        \
    __builtin_amdgcn_s_setprio(1);                                            \
    _Pragma("unroll") for (int mi_ = 0; mi_ < 4; ++mi_)                       \
      _Pragma("unroll") for (int ni_ = 0; ni_ < NF; ++ni_)                    \
        _Pragma("unroll") for (int kk_ = 0; kk_ < 2; ++kk_)                   \
          acc[(MH)*4 + mi_][(NH)*NF + ni_] =                                  \
              __builtin_amdgcn_mfma_f32_16x16x32_bf16(                        \
                  AS[mi_][kk_], BS[ni_][kk_],                                 \
                  acc[(MH)*4 + mi_][(NH)*NF + ni_], 0, 0, 0);                 \
    __builtin_amdgcn_s_setprio(0);                                            \
  } while (0)

  // One K-tile iteration. Phase p issues ds_reads consumed by phase p+1's
  // MFMA; staging slots are free by consumption-derivation (see analysis).
#define GITER(T, BRD, BWR, Wp1, Wp2, Wp3, Wp4, ST, RDN)                       \
  do {                                                                        \
    const int b_ = (T)&1;                                                     \
    /* P1: read Bh1(t); MFMA Q00 = a0 x BRD */                                \
    RDB(b_, 1, b1);                                                           \
    vmwait<Wp1>();                                                            \
    barrier_raw();                                                            \
    MMQ(a0, BRD, 0, 0);                                                       \
    barrier_raw();                                                            \
    /* P2: read Ah1(t); stage Ah0/Bh0(t+2); MFMA Q01 = a0 x b1 */             \
    RDA(b_, 1, a1);                                                           \
    if (ST) { STA((T) + 2, 0, b_); STB((T) + 2, 0, b_); }                     \
    vmwait<Wp2>();                                                            \
    barrier_raw();                                                            \
    MMQ(a0, b1, 0, 1);                                                        \
    barrier_raw();                                                            \
    /* P3: read Ah0(t+1); stage Bh1(t+2); MFMA Q11 = a1 x b1 */               \
    if (RDN) RDA(b_ ^ 1, 0, a0);                                              \
    if (ST) STB((T) + 2, 1, b_);                                              \
    vmwait<Wp3>();                                                            \
    barrier_raw();                                                            \
    MMQ(a1, b1, 1, 1);                                                        \
    barrier_raw();                                                            \
    /* P4: read Bh0(t+1); stage Ah1(t+2); MFMA Q10 = a1 x BRD */              \
    if (RDN) RDB(b_ ^ 1, 0, BWR);                                             \
    if (ST) STA((T) + 2, 1, b_);                                              \
    vmwait<Wp4>();                                                            \
    barrier_raw();                                                            \
    MMQ(a1, BRD, 1, 0);                                                       \
    barrier_raw();                                                            \
  } while (0)

  // ---- prologue: stage tiles 0,1 in steady order [Ah0,Bh0,Bh1,Ah1] ----
  STA(0, 0, 0); STB(0, 0, 0); STB(0, 1, 0); STA(0, 1, 0);
  STA(1, 0, 1); STB(1, 0, 1); STB(1, 1, 1); STA(1, 1, 1);
  vmwait<3 * SA + 2 * SB>();  // Ah0/Bh0/Bh1(0) resident after barrier
  barrier_raw();
  RDA(0, 0, a0);
  RDB(0, 0, b0);

  for (int tt = 0; tt + 4 <= NT; tt += 2) {
    GITER(tt,     b0,  b0n, W1, W2,  W3,  W4,  true,  true);
    GITER(tt + 1, b0n, b0,  W1, W2,  W3,  W4,  true,  true);
  }
  GITER(NT - 2, b0,  b0n, W1, W2a, W3a, W4a, false, true);
  GITER(NT - 1, b0n, b0,  0,  0,   0,   0,   false, false);

#undef GITER
#undef MMQ
#undef RDA
#undef RDB
#undef STA
#undef STB

  // ---- epilogue: C/D frag layout col = lane&15, row = (lane>>4)*4 + reg ----
  const int orow0 = bm * 256 + wm * 64;
  const int ocol0 = bn * BN + wn * WN;
#pragma unroll
  for (int mh = 0; mh < 2; ++mh)
#pragma unroll
    for (int nh = 0; nh < 2; ++nh)
#pragma unroll
      for (int ni = 0; ni < NF; ++ni) {
        int col = ocol0 + nh * BH + ni * 16 + lr;
        float bv = bias[col];
#pragma unroll
        for (int mi = 0; mi < 4; ++mi)
#pragma unroll
          for (int r = 0; r < 4; ++r) {
            int row = orow0 + mh * 128 + mi * 16 + lk * 4 + r;
            float val = acc[mh * 4 + mi][nh * NF + ni][r];
            if (SPLITK) {
              if (sk == 0)
                ((float*)C)[(size_t)row * N + col] = val + bv;
              else
                C2[(size_t)row * N + col] = f2b(val);
            } else {
              val += bv;
              if (RELU) val = fmaxf(val, 0.f);
              if (OUTB)
                ((unsigned short*)C)[(size_t)row * N + col] = f2b(val);
              else
                ((float*)C)[(size_t)row * N + col] = val;
            }
          }
      }
}

// ---------------- per-position head attention --------------------------------
__global__ __launch_bounds__(256) void attn_kernel(
    const unsigned short* __restrict__ qkv, const int* __restrict__ mask,
    unsigned short* __restrict__ outb) {
  __shared__ float sq[16][68], sk[16][68], sv[16][68];
  __shared__ float sp[16][17];
  const int pos = blockIdx.x;           // n*2048 + s
  const int n = pos >> 11, s = pos & 2047;
  const int tid = threadIdx.x;
  const unsigned short* row = qkv + (size_t)pos * 3072;
#pragma unroll
  for (int it = 0; it < 3; ++it) {
    uint2 raw = *(const uint2*)(row + it * 1024 + tid * 4);
    float f0 = b2f((unsigned short)(raw.x & 0xffffu));
    float f1 = b2f((unsigned short)(raw.x >> 16));
    float f2 = b2f((unsigned short)(raw.y & 0xffffu));
    float f3 = b2f((unsigned short)(raw.y >> 16));
    float(*dst)[68] = (it == 0) ? sq : (it == 1) ? sk : sv;
    int r = tid >> 4, d = (tid & 15) * 4;
    dst[r][d] = f0; dst[r][d + 1] = f1; dst[r][d + 2] = f2; dst[r][d + 3] = f3;
  }
  __syncthreads();
  {
    const int i = tid >> 4, j = tid & 15;
    float e = 0.f;
#pragma unroll
    for (int d = 0; d < 64; d += 4) {
      float4 qa = *(const float4*)&sq[i][d];
      float4 kb = *(const float4*)&sk[j][d];
      e += qa.x * kb.x + qa.y * kb.y + qa.z * kb.z + qa.w * kb.w;
    }
    if (mask[n * 16 + j] == 0) e = -1e20f;
    e *= 0.125f;  // 1/sqrt(64)
    float mx = e;
#pragma unroll
    for (int o = 8; o > 0; o >>= 1) mx = fmaxf(mx, __shfl_xor(mx, o, 16));
    float pe = __expf(e - mx);
    float sm = pe;
#pragma unroll
    for (int o = 8; o > 0; o >>= 1) sm += __shfl_xor(sm, o, 16);
    sp[i][j] = pe / sm;
  }
  __syncthreads();
  {
    const int w = tid >> 6, d = tid & 63;
    float o0 = 0, o1 = 0, o2 = 0, o3 = 0;
#pragma unroll
    for (int l = 0; l < 16; ++l) {
      float vv = sv[l][d];
      o0 += sp[w][l] * vv;      o1 += sp[w + 4][l] * vv;
      o2 += sp[w + 8][l] * vv;  o3 += sp[w + 12][l] * vv;
    }
    outb[(((size_t)n * 16 + w     ) * 2048 + s) * 64 + d] = f2b(o0);
    outb[(((size_t)n * 16 + w + 4 ) * 2048 + s) * 64 + d] = f2b(o1);
    outb[(((size_t)n * 16 + w + 8 ) * 2048 + s) * 64 + d] = f2b(o2);
    outb[(((size_t)n * 16 + w + 12) * 2048 + s) * 64 + d] = f2b(o3);
  }
}

// ---------------- LayerNorm(A [+ P2] + R) * g + beta -------------------------
__global__ __launch_bounds__(256) void ln_kernel(
    const float* __restrict__ A, const unsigned short* __restrict__ P2,
    const float* __restrict__ R,
    const float* __restrict__ g, const float* __restrict__ be,
    float* __restrict__ outf, unsigned short* __restrict__ outb) {
  const int row = blockIdx.x, tid = threadIdx.x;
  const size_t base = (size_t)row * 1024 + tid * 4;
  float4 a = *(const float4*)(A + base);
  float4 r = *(const float4*)(R + base);
  float x0 = a.x + r.x, x1 = a.y + r.y, x2 = a.z + r.z, x3 = a.w + r.w;
  if (P2) {
    uint2 p = *(const uint2*)(P2 + base);
    x0 += b2f((unsigned short)(p.x & 0xffffu));
    x1 += b2f((unsigned short)(p.x >> 16));
    x2 += b2f((unsigned short)(p.y & 0xffffu));
    x3 += b2f((unsigned short)(p.y >> 16));
  }
  float s = x0 + x1 + x2 + x3;
#pragma unroll
  for (int o = 32; o > 0; o >>= 1) s += __shfl_xor(s, o);
  __shared__ float red[4];
  const int lane = tid & 63, wv = tid >> 6;
  if (lane == 0) red[wv] = s;
  __syncthreads();
  float mean = (red[0] + red[1] + red[2] + red[3]) * (1.f / 1024.f);
  float d0 = x0 - mean, d1 = x1 - mean, d2 = x2 - mean, d3 = x3 - mean;
  float q = d0 * d0 + d1 * d1 + d2 * d2 + d3 * d3;
#pragma unroll
  for (int o = 32; o > 0; o >>= 1) q += __shfl_xor(q, o);
  __syncthreads();  // everyone done reading red
  if (lane == 0) red[wv] = q;
  __syncthreads();
  float var = (red[0] + red[1] + red[2] + red[3]) * (1.f / 1024.f);
  float rs = rsqrtf(var + 1e-5f);
  const int col = tid * 4;
  float4 gv = *(const float4*)(g + col);
  float4 bv = *(const float4*)(be + col);
  float y0 = d0 * rs * gv.x + bv.x;
  float y1 = d1 * rs * gv.y + bv.y;
  float y2 = d2 * rs * gv.z + bv.z;
  float y3 = d3 * rs * gv.w + bv.w;
  *(float4*)(outf + base) = make_float4(y0, y1, y2, y3);
  if (outb) {
    uint32_t lo = (uint32_t)f2b(y0) | ((uint32_t)f2b(y1) << 16);
    uint32_t hi = (uint32_t)f2b(y2) | ((uint32_t)f2b(y3) << 16);
    *(uint2*)(outb + base) = make_uint2(lo, hi);
  }
}

// ---------------- launch ------------------------------------------------------
extern "C" void kernel_launch(void* const* d_in, const int* in_sizes, int n_in,
                              void* d_out, int out_size, void* d_ws,
                              size_t ws_size, hipStream_t stream) {
  (void)in_sizes; (void)n_in; (void)out_size; (void)ws_size;
  const float* x     = (const float*)d_in[0];
  const float* Wqkv  = (const float*)d_in[1];
  const float* bqkv  = (const float*)d_in[2];
  const float* Wo    = (const float*)d_in[3];
  const float* bo    = (const float*)d_in[4];
  const float* g1    = (const float*)d_in[5];
  const float* beta1 = (const float*)d_in[6];
  const float* W1    = (const float*)d_in[7];
  const float* bf1   = (const float*)d_in[8];
  const float* W2    = (const float*)d_in[9];
  const float* bf2   = (const float*)d_in[10];
  const float* g2    = (const float*)d_in[11];
  const float* beta2 = (const float*)d_in[12];
  const int*   mask  = (const int*)d_in[13];
  float* out = (float*)d_out;

  char* ws = (char*)d_ws;
  unsigned short* WqkvT = (unsigned short*)(ws + 0);          //  6 MB
  unsigned short* WoT   = (unsigned short*)(ws + 6291456);    //  2 MB
  unsigned short* W1T   = (unsigned short*)(ws + 8388608);    //  8 MB
  unsigned short* W2T   = (unsigned short*)(ws + 16777216);   //  8 MB
  unsigned short* xb    = (unsigned short*)(ws + 25165824);   // 16 MB (dead after G1)
  float*          h_f   = (float*)(ws + 41943040);            // 32 MB
  unsigned short* h_b   = (unsigned short*)(ws + 75497472);   // 16 MB
  float*          ao2   = (float*)(ws + 92274688);            // 32 MB (reused: ff2)
  unsigned short* qkvb  = (unsigned short*)(ws + 125829120);  // 48 MB (reused: ff1 lo)
  unsigned short* aob   = (unsigned short*)(ws + 176160768);  // 16 MB (reused: ff1 hi)
  unsigned short* ff1   = qkvb;   // 64 MB spanning qkvb+aob (dead by then)
  float*          ff2   = ao2;    // dead after LN1
  unsigned short* ff2p2 = xb;     // 16 MB split-K bf16 partial (xb dead)

  transpose_cvt_kernel<<<dim3(96, 32),  dim3(32, 8), 0, stream>>>(Wqkv, WqkvT, 1024, 3072);
  transpose_cvt_kernel<<<dim3(32, 32),  dim3(32, 8), 0, stream>>>(Wo,   WoT,   1024, 1024);
  transpose_cvt_kernel<<<dim3(128, 32), dim3(32, 8), 0, stream>>>(W1,   W1T,   1024, 4096);
  transpose_cvt_kernel<<<dim3(32, 128), dim3(32, 8), 0, stream>>>(W2,   W2T,   4096, 1024);
  cvt_bf16_kernel<<<2048, 256, 0, stream>>>(x, xb, 8192 * 1024 / 4);

  // grids: (M/256) x (N/BN) [x2 split-K], 1D with in-kernel XCD swizzle
  gemm8p_kernel<256, false, true, false><<<dim3(32 * 12), 512, 0, stream>>>(
      xb, WqkvT, bqkv, qkvb, nullptr, 8192, 3072, 1024, 1024, 12);
  attn_kernel<<<8192, 256, 0, stream>>>(qkvb, mask, aob);
  gemm8p_kernel<128, false, false, false><<<dim3(32 * 8), 512, 0, stream>>>(
      aob, WoT, bo, ao2, nullptr, 8192, 1024, 1024, 1024, 8);
  ln_kernel<<<8192, 256, 0, stream>>>(ao2, nullptr, x, g1, beta1, h_f, h_b);
  gemm8p_kernel<256, false, true, true><<<dim3(32 * 16), 512, 0, stream>>>(
      h_b, W1T, bf1, ff1, nullptr, 8192, 4096, 1024, 1024, 16);
  gemm8p_kernel<256, true, false, false><<<dim3(32 * 8), 512, 0, stream>>>(
      ff1, W2T, bf2, ff2, ff2p2, 8192, 1024, 4096, 2048, 4);
  ln_kernel<<<8192, 256, 0, stream>>>(ff2, ff2p2, h_f, g2, beta2, out, nullptr);
}

// Round 6
// 315.600 us; speedup vs baseline: 2.2046x; 2.2046x over previous
//
#include <hip/hip_runtime.h>
#include <cstdint>
#include <cstddef>

// EncoderLayer: x(4,2048,1024) f32.
//   prep:  W* (KxN f32) -> W*T (NxK bf16); x f32 -> xb bf16
//   G1: qkv_b  = xb @ WqkvT + bqkv              (8192x3072, bf16 out)  BN=256
//   attn: per-position 16x16 head attention, out (N,H,S,hd) = scrambled reshape
//   G2: ao2    = aob @ WoT + bo                 (8192x1024, f32 out)   BN=128
//   LN1: h = LN(ao2 + x)  -> h_f (f32) + h_b (bf16)
//   G3: ff1_b  = relu(h_b @ W1T + bf1)          (8192x4096, bf16 out)  BN=256
//   G4: ff2    = ff1_b @ W2T + bf2   SPLIT-K=2  (8192x1024)            BN=256
//   LN2: out = LN(ff2 + p2 + h_f)               (f32 -> d_out)
//
// GEMM v4 "cluster pipeline": 8 clusters per K-tile, each = {ds_reads for a
// cluster >=2 ahead | stage issue | counted vmcnt | barrier | 4*NF MFMA}.
// Register rotation: 2 A-sets (aX,aY; 16 regs each) + 3 B-sets (bP,bQ,bR;
// 8*NF regs each) -- 56 arch regs of fragments + 128 AGPR acc fits the
// 256-unified-regs/wave budget (2 waves/SIMD @ 128KB LDS). Cluster order
// (mh,nh,kk): (0,0,0)(0,1,0)(1,1,0)(1,0,0)(1,0,1)(1,1,1)(0,1,1)(0,0,1).
// Stages: C3:Bh0(t+2) C4:Ah1(t+2) C5:Bh1(t+2) C6:Ah0(t+2) -- each exactly one
// barrier after its slot's last read. Waits: end-C5 vmcnt(3SA+3SB), end-C6
// vmcnt(2SA+2SB) (derived; all other deps complete transitively).

using f32x4  = __attribute__((ext_vector_type(4))) float;
using bf16x8 = __attribute__((ext_vector_type(8))) __bf16;

__device__ __forceinline__ unsigned short f2b(float f) {
  union { float f; uint32_t u; } v; v.f = f;
  uint32_t r = v.u + 0x7FFFu + ((v.u >> 16) & 1u);  // RNE
  return (unsigned short)(r >> 16);
}
__device__ __forceinline__ float b2f(unsigned short u) {
  union { uint32_t u; float f; } v; v.u = ((uint32_t)u) << 16;
  return v.f;
}

__device__ __forceinline__ void gload_lds16(const unsigned short* g,
                                            unsigned short* l) {
  __builtin_amdgcn_global_load_lds(
      (const __attribute__((address_space(1))) unsigned int*)g,
      (__attribute__((address_space(3))) unsigned int*)l, 16, 0, 0);
}

#define MEMBAR() asm volatile("" ::: "memory")
__device__ __forceinline__ void barrier_raw() {
  MEMBAR();
  __builtin_amdgcn_s_barrier();
  MEMBAR();
}
template <int N>
__device__ __forceinline__ void vmwait() {
  static_assert(N >= 0 && N <= 12, "vmcnt range");
  if constexpr (N == 0)  asm volatile("s_waitcnt vmcnt(0)" ::: "memory");
  if constexpr (N == 1)  asm volatile("s_waitcnt vmcnt(1)" ::: "memory");
  if constexpr (N == 2)  asm volatile("s_waitcnt vmcnt(2)" ::: "memory");
  if constexpr (N == 3)  asm volatile("s_waitcnt vmcnt(3)" ::: "memory");
  if constexpr (N == 4)  asm volatile("s_waitcnt vmcnt(4)" ::: "memory");
  if constexpr (N == 5)  asm volatile("s_waitcnt vmcnt(5)" ::: "memory");
  if constexpr (N == 6)  asm volatile("s_waitcnt vmcnt(6)" ::: "memory");
  if constexpr (N == 7)  asm volatile("s_waitcnt vmcnt(7)" ::: "memory");
  if constexpr (N == 8)  asm volatile("s_waitcnt vmcnt(8)" ::: "memory");
  if constexpr (N == 9)  asm volatile("s_waitcnt vmcnt(9)" ::: "memory");
  if constexpr (N == 10) asm volatile("s_waitcnt vmcnt(10)" ::: "memory");
  if constexpr (N == 11) asm volatile("s_waitcnt vmcnt(11)" ::: "memory");
  if constexpr (N == 12) asm volatile("s_waitcnt vmcnt(12)" ::: "memory");
}

// ---------------- weight transpose + convert: W (KxN f32) -> WT (NxK bf16) ----
__global__ __launch_bounds__(256) void transpose_cvt_kernel(
    const float* __restrict__ W, unsigned short* __restrict__ WT, int K, int N) {
  __shared__ float tile[32][33];
  const int j0 = blockIdx.x * 32, k0 = blockIdx.y * 32;
  const int tx = threadIdx.x, ty = threadIdx.y;
#pragma unroll
  for (int i = 0; i < 4; ++i)
    tile[ty + 8 * i][tx] = W[(size_t)(k0 + ty + 8 * i) * N + j0 + tx];
  __syncthreads();
#pragma unroll
  for (int i = 0; i < 4; ++i)
    WT[(size_t)(j0 + ty + 8 * i) * K + k0 + tx] = f2b(tile[tx][ty + 8 * i]);
}

// ---------------- f32 -> bf16 elementwise ------------------------------------
__global__ __launch_bounds__(256) void cvt_bf16_kernel(
    const float* __restrict__ in, unsigned short* __restrict__ out, int n4) {
  for (int i = blockIdx.x * blockDim.x + threadIdx.x; i < n4;
       i += gridDim.x * blockDim.x) {
    float4 v = ((const float4*)in)[i];
    uint32_t lo = (uint32_t)f2b(v.x) | ((uint32_t)f2b(v.y) << 16);
    uint32_t hi = (uint32_t)f2b(v.z) | ((uint32_t)f2b(v.w) << 16);
    ((uint2*)out)[i] = make_uint2(lo, hi);
  }
}

// ---------------- GEMM: C(MxN) = A(MxK,bf16) * B^T(NxK,bf16) + bias ----------
template <int BN, bool SPLITK, bool OUTB, bool RELU>
__global__ __launch_bounds__(512, 2) void gemmc_kernel(
    const unsigned short* __restrict__ A, const unsigned short* __restrict__ B,
    const float* __restrict__ bias, void* __restrict__ C,
    unsigned short* __restrict__ C2, int M, int N, int Ks, int Kd, int nbn) {
  constexpr int NF   = BN / 128;        // n-frags per cluster per wave
  constexpr int WN   = BN / 8;          // wave col extent within a B-half
  constexpr int BH   = BN / 2;          // B half rows
  constexpr int SA   = 2;               // gload issues per A-half
  constexpr int SB   = NF;              // gload issues per B-half
  constexpr int ASTR = (256 + BN) * 64; // elements per dbuf
  constexpr int W5s  = 3 * SA + 3 * SB; // steady end-C5 wait
  constexpr int W6s  = 2 * SA + 2 * SB; // steady end-C6 wait
  constexpr int W5t  = 2 * SA + SB;     // tail (t = NT-2) end-C5 wait

  __shared__ unsigned short lds[2 * ASTR];  // 128 KB (BN=256) / 96 KB (BN=128)

  const int tid  = threadIdx.x;
  const int lane = tid & 63, wave = tid >> 6;
  const int wm = wave >> 2, wn = wave & 3;  // 2 x 4 wave grid
  const int lr = lane & 15, lk = lane >> 4;
  const int x7 = lr & 7;

  // XCD-chunked swizzle, bn-fastest (all grids % 8 == 0)
  const int nwg = gridDim.x, cpx = nwg >> 3, id = blockIdx.x;
  const int wg = (id & 7) * cpx + (id >> 3);
  int bm, bn, sk;
  if (SPLITK) { bm = wg >> 3; bn = (wg & 7) >> 1; sk = wg & 1; }
  else        { bm = wg / nbn; bn = wg % nbn; sk = 0; }

  const unsigned short* Ab = A + (size_t)bm * 256 * Ks + (size_t)sk * Kd;
  const unsigned short* Bb = B + (size_t)bn * BN * Ks + (size_t)sk * Kd;

  // staging: per issue, 512 lanes x 16B = 64 rows x 128B; source pre-swizzled
  const int srow = tid >> 3;                       // row within 64-row group
  const int scol = ((tid & 7) ^ (srow & 7)) * 8;   // swizzled col element
  const int ldst = wave * 8 * 64;                  // wave dest offset (elems)

  const int NT = Kd >> 6;  // >= 4

  f32x4 acc[8][2 * NF] = {};
  bf16x8 aX[4], aY[4], bP[NF], bQ[NF], bR[NF];

#define STA(T, H, BUF)                                                        \
  _Pragma("unroll") for (int i_ = 0; i_ < SA; ++i_)                          \
      gload_lds16(Ab + (size_t)((H)*128 + i_ * 64 + srow) * Ks + (T)*64 + scol,\
                  &lds[(BUF)*ASTR + ((H)*128 + i_ * 64) * 64 + ldst])
#define STB(T, H, BUF)                                                        \
  _Pragma("unroll") for (int i_ = 0; i_ < SB; ++i_)                          \
      gload_lds16(Bb + (size_t)((H)*BH + i_ * 64 + srow) * Ks + (T)*64 + scol, \
                  &lds[(BUF)*ASTR + 256 * 64 + ((H)*BH + i_ * 64) * 64 + ldst])
#define RDA(DST, BUF, MH, KK)                                                 \
  _Pragma("unroll") for (int mi_ = 0; mi_ < 4; ++mi_)                         \
      DST[mi_] = *(const bf16x8*)&lds[(BUF)*ASTR +                            \
          ((MH)*128 + wm * 64 + mi_ * 16 + lr) * 64 + (((KK)*4 + lk) ^ x7) * 8]
#define RDB(DST, BUF, NH, KK)                                                 \
  _Pragma("unroll") for (int ni_ = 0; ni_ < NF; ++ni_)                        \
      DST[ni_] = *(const bf16x8*)&lds[(BUF)*ASTR + 256 * 64 +                 \
          ((NH)*BH + wn * WN + ni_ * 16 + lr) * 64 + (((KK)*4 + lk) ^ x7) * 8]
#define MM(AS, BS, MH, NH)                                                    \
  do {                                                                        \
    __builtin_amdgcn_s_setprio(1);                                            \
    _Pragma("unroll") for (int mi_ = 0; mi_ < 4; ++mi_)                       \
      _Pragma("unroll") for (int ni_ = 0; ni_ < NF; ++ni_)                    \
        acc[(MH)*4 + mi_][(NH)*NF + ni_] =                                    \
            __builtin_amdgcn_mfma_f32_16x16x32_bf16(                          \
                AS[mi_], BS[ni_], acc[(MH)*4 + mi_][(NH)*NF + ni_], 0, 0, 0); \
    __builtin_amdgcn_s_setprio(0);                                            \
  } while (0)

  // One K-tile = 8 clusters. Reads land >=2 clusters before consumption;
  // each LDS slot is re-staged exactly one barrier after its last read.
#define GITER(T, ST, RDN, W5, W6)                                             \
  do {                                                                        \
    const int p_ = (T)&1;                                                     \
    /* C1 (0,0,k0) */                                                         \
    RDA(aY, p_, 1, 0);                                                        \
    barrier_raw(); MM(aX, bP, 0, 0);                                          \
    /* C2 (0,1,k0) */                                                         \
    RDB(bR, p_, 0, 1);                                                        \
    barrier_raw(); MM(aX, bQ, 0, 1);                                          \
    /* C3 (1,1,k0) */                                                         \
    RDA(aX, p_, 1, 1);                                                        \
    if (ST) STB((T) + 2, 0, p_);                                              \
    barrier_raw(); MM(aY, bQ, 1, 1);                                          \
    /* C4 (1,0,k0) */                                                         \
    RDB(bQ, p_, 1, 1);                                                        \
    if (ST) STA((T) + 2, 1, p_);                                              \
    barrier_raw(); MM(aY, bP, 1, 0);                                          \
    /* C5 (1,0,k1) */                                                         \
    RDA(aY, p_, 0, 1);                                                        \
    if (ST) STB((T) + 2, 1, p_);                                              \
    vmwait<W5>();                                                             \
    barrier_raw(); MM(aX, bR, 1, 0);                                          \
    /* C6 (1,1,k1) */                                                         \
    if (RDN) RDB(bP, p_ ^ 1, 0, 0);                                           \
    if (ST) STA((T) + 2, 0, p_);                                              \
    vmwait<W6>();                                                             \
    barrier_raw(); MM(aX, bQ, 1, 1);                                          \
    /* C7 (0,1,k1) */                                                         \
    if (RDN) RDA(aX, p_ ^ 1, 0, 0);                                           \
    barrier_raw(); MM(aY, bQ, 0, 1);                                          \
    /* C8 (0,0,k1) */                                                         \
    if (RDN) RDB(bQ, p_ ^ 1, 1, 0);                                           \
    barrier_raw(); MM(aY, bR, 0, 0);                                          \
  } while (0)

  // ---- prologue: stage tile0 (any order) + tile1 (Bh0 FIRST) ----
  STA(0, 0, 0); STB(0, 0, 0); STB(0, 1, 0); STA(0, 1, 0);
  STB(1, 0, 1); STA(1, 0, 1); STB(1, 1, 1); STA(1, 1, 1);
  vmwait<W6s>();  // tile0 fully resident; tile1's loads stay in flight
  barrier_raw();
  RDA(aX, 0, 0, 0);   // A0(0,k0) -> C1,C2
  RDB(bP, 0, 0, 0);   // B0(0,k0) -> C1,C4
  RDB(bQ, 0, 1, 0);   // B0(1,k0) -> C2,C3

  for (int t = 0; t + 2 < NT; ++t) GITER(t, true, true, W5s, W6s);
  GITER(NT - 2, false, true, W5t, 0);
  GITER(NT - 1, false, false, 0, 0);

#undef GITER
#undef MM
#undef RDA
#undef RDB
#undef STA
#undef STB

  // ---- epilogue: C/D frag layout col = lane&15, row = (lane>>4)*4 + reg ----
  const int orow0 = bm * 256 + wm * 64;
  const int ocol0 = bn * BN + wn * WN;
#pragma unroll
  for (int mh = 0; mh < 2; ++mh)
#pragma unroll
    for (int nh = 0; nh < 2; ++nh)
#pragma unroll
      for (int ni = 0; ni < NF; ++ni) {
        int col = ocol0 + nh * BH + ni * 16 + lr;
        float bv = bias[col];
#pragma unroll
        for (int mi = 0; mi < 4; ++mi)
#pragma unroll
          for (int r = 0; r < 4; ++r) {
            int row = orow0 + mh * 128 + mi * 16 + lk * 4 + r;
            float val = acc[mh * 4 + mi][nh * NF + ni][r];
            if (SPLITK) {
              if (sk == 0)
                ((float*)C)[(size_t)row * N + col] = val + bv;
              else
                C2[(size_t)row * N + col] = f2b(val);
            } else {
              val += bv;
              if (RELU) val = fmaxf(val, 0.f);
              if (OUTB)
                ((unsigned short*)C)[(size_t)row * N + col] = f2b(val);
              else
                ((float*)C)[(size_t)row * N + col] = val;
            }
          }
      }
}

// ---------------- per-position head attention --------------------------------
__global__ __launch_bounds__(256) void attn_kernel(
    const unsigned short* __restrict__ qkv, const int* __restrict__ mask,
    unsigned short* __restrict__ outb) {
  __shared__ float sq[16][68], sk[16][68], sv[16][68];
  __shared__ float sp[16][17];
  const int pos = blockIdx.x;           // n*2048 + s
  const int n = pos >> 11, s = pos & 2047;
  const int tid = threadIdx.x;
  const unsigned short* row = qkv + (size_t)pos * 3072;
#pragma unroll
  for (int it = 0; it < 3; ++it) {
    uint2 raw = *(const uint2*)(row + it * 1024 + tid * 4);
    float f0 = b2f((unsigned short)(raw.x & 0xffffu));
    float f1 = b2f((unsigned short)(raw.x >> 16));
    float f2 = b2f((unsigned short)(raw.y & 0xffffu));
    float f3 = b2f((unsigned short)(raw.y >> 16));
    float(*dst)[68] = (it == 0) ? sq : (it == 1) ? sk : sv;
    int r = tid >> 4, d = (tid & 15) * 4;
    dst[r][d] = f0; dst[r][d + 1] = f1; dst[r][d + 2] = f2; dst[r][d + 3] = f3;
  }
  __syncthreads();
  {
    const int i = tid >> 4, j = tid & 15;
    float e = 0.f;
#pragma unroll
    for (int d = 0; d < 64; d += 4) {
      float4 qa = *(const float4*)&sq[i][d];
      float4 kb = *(const float4*)&sk[j][d];
      e += qa.x * kb.x + qa.y * kb.y + qa.z * kb.z + qa.w * kb.w;
    }
    if (mask[n * 16 + j] == 0) e = -1e20f;
    e *= 0.125f;  // 1/sqrt(64)
    float mx = e;
#pragma unroll
    for (int o = 8; o > 0; o >>= 1) mx = fmaxf(mx, __shfl_xor(mx, o, 16));
    float pe = __expf(e - mx);
    float sm = pe;
#pragma unroll
    for (int o = 8; o > 0; o >>= 1) sm += __shfl_xor(sm, o, 16);
    sp[i][j] = pe / sm;
  }
  __syncthreads();
  {
    const int w = tid >> 6, d = tid & 63;
    float o0 = 0, o1 = 0, o2 = 0, o3 = 0;
#pragma unroll
    for (int l = 0; l < 16; ++l) {
      float vv = sv[l][d];
      o0 += sp[w][l] * vv;      o1 += sp[w + 4][l] * vv;
      o2 += sp[w + 8][l] * vv;  o3 += sp[w + 12][l] * vv;
    }
    outb[(((size_t)n * 16 + w     ) * 2048 + s) * 64 + d] = f2b(o0);
    outb[(((size_t)n * 16 + w + 4 ) * 2048 + s) * 64 + d] = f2b(o1);
    outb[(((size_t)n * 16 + w + 8 ) * 2048 + s) * 64 + d] = f2b(o2);
    outb[(((size_t)n * 16 + w + 12) * 2048 + s) * 64 + d] = f2b(o3);
  }
}

// ---------------- LayerNorm(A [+ P2] + R) * g + beta -------------------------
__global__ __launch_bounds__(256) void ln_kernel(
    const float* __restrict__ A, const unsigned short* __restrict__ P2,
    const float* __restrict__ R,
    const float* __restrict__ g, const float* __restrict__ be,
    float* __restrict__ outf, unsigned short* __restrict__ outb) {
  const int row = blockIdx.x, tid = threadIdx.x;
  const size_t base = (size_t)row * 1024 + tid * 4;
  float4 a = *(const float4*)(A + base);
  float4 r = *(const float4*)(R + base);
  float x0 = a.x + r.x, x1 = a.y + r.y, x2 = a.z + r.z, x3 = a.w + r.w;
  if (P2) {
    uint2 p = *(const uint2*)(P2 + base);
    x0 += b2f((unsigned short)(p.x & 0xffffu));
    x1 += b2f((unsigned short)(p.x >> 16));
    x2 += b2f((unsigned short)(p.y & 0xffffu));
    x3 += b2f((unsigned short)(p.y >> 16));
  }
  float s = x0 + x1 + x2 + x3;
#pragma unroll
  for (int o = 32; o > 0; o >>= 1) s += __shfl_xor(s, o);
  __shared__ float red[4];
  const int lane = tid & 63, wv = tid >> 6;
  if (lane == 0) red[wv] = s;
  __syncthreads();
  float mean = (red[0] + red[1] + red[2] + red[3]) * (1.f / 1024.f);
  float d0 = x0 - mean, d1 = x1 - mean, d2 = x2 - mean, d3 = x3 - mean;
  float q = d0 * d0 + d1 * d1 + d2 * d2 + d3 * d3;
#pragma unroll
  for (int o = 32; o > 0; o >>= 1) q += __shfl_xor(q, o);
  __syncthreads();  // everyone done reading red
  if (lane == 0) red[wv] = q;
  __syncthreads();
  float var = (red[0] + red[1] + red[2] + red[3]) * (1.f / 1024.f);
  float rs = rsqrtf(var + 1e-5f);
  const int col = tid * 4;
  float4 gv = *(const float4*)(g + col);
  float4 bv = *(const float4*)(be + col);
  float y0 = d0 * rs * gv.x + bv.x;
  float y1 = d1 * rs * gv.y + bv.y;
  float y2 = d2 * rs * gv.z + bv.z;
  float y3 = d3 * rs * gv.w + bv.w;
  *(float4*)(outf + base) = make_float4(y0, y1, y2, y3);
  if (outb) {
    uint32_t lo = (uint32_t)f2b(y0) | ((uint32_t)f2b(y1) << 16);
    uint32_t hi = (uint32_t)f2b(y2) | ((uint32_t)f2b(y3) << 16);
    *(uint2*)(outb + base) = make_uint2(lo, hi);
  }
}

// ---------------- launch ------------------------------------------------------
extern "C" void kernel_launch(void* const* d_in, const int* in_sizes, int n_in,
                              void* d_out, int out_size, void* d_ws,
                              size_t ws_size, hipStream_t stream) {
  (void)in_sizes; (void)n_in; (void)out_size; (void)ws_size;
  const float* x     = (const float*)d_in[0];
  const float* Wqkv  = (const float*)d_in[1];
  const float* bqkv  = (const float*)d_in[2];
  const float* Wo    = (const float*)d_in[3];
  const float* bo    = (const float*)d_in[4];
  const float* g1    = (const float*)d_in[5];
  const float* beta1 = (const float*)d_in[6];
  const float* W1    = (const float*)d_in[7];
  const float* bf1   = (const float*)d_in[8];
  const float* W2    = (const float*)d_in[9];
  const float* bf2   = (const float*)d_in[10];
  const float* g2    = (const float*)d_in[11];
  const float* beta2 = (const float*)d_in[12];
  const int*   mask  = (const int*)d_in[13];
  float* out = (float*)d_out;

  char* ws = (char*)d_ws;
  unsigned short* WqkvT = (unsigned short*)(ws + 0);          //  6 MB
  unsigned short* WoT   = (unsigned short*)(ws + 6291456);    //  2 MB
  unsigned short* W1T   = (unsigned short*)(ws + 8388608);    //  8 MB
  unsigned short* W2T   = (unsigned short*)(ws + 16777216);   //  8 MB
  unsigned short* xb    = (unsigned short*)(ws + 25165824);   // 16 MB (dead after G1)
  float*          h_f   = (float*)(ws + 41943040);            // 32 MB
  unsigned short* h_b   = (unsigned short*)(ws + 75497472);   // 16 MB
  float*          ao2   = (float*)(ws + 92274688);            // 32 MB (reused: ff2)
  unsigned short* qkvb  = (unsigned short*)(ws + 125829120);  // 48 MB (reused: ff1 lo)
  unsigned short* aob   = (unsigned short*)(ws + 176160768);  // 16 MB (reused: ff1 hi)
  unsigned short* ff1   = qkvb;   // 64 MB spanning qkvb+aob (dead by then)
  float*          ff2   = ao2;    // dead after LN1
  unsigned short* ff2p2 = xb;     // 16 MB split-K bf16 partial (xb dead)

  transpose_cvt_kernel<<<dim3(96, 32),  dim3(32, 8), 0, stream>>>(Wqkv, WqkvT, 1024, 3072);
  transpose_cvt_kernel<<<dim3(32, 32),  dim3(32, 8), 0, stream>>>(Wo,   WoT,   1024, 1024);
  transpose_cvt_kernel<<<dim3(128, 32), dim3(32, 8), 0, stream>>>(W1,   W1T,   1024, 4096);
  transpose_cvt_kernel<<<dim3(32, 128), dim3(32, 8), 0, stream>>>(W2,   W2T,   4096, 1024);
  cvt_bf16_kernel<<<2048, 256, 0, stream>>>(x, xb, 8192 * 1024 / 4);

  // grids: (M/256) x (N/BN) [x2 split-K], 1D with in-kernel XCD swizzle
  gemmc_kernel<256, false, true, false><<<dim3(32 * 12), 512, 0, stream>>>(
      xb, WqkvT, bqkv, qkvb, nullptr, 8192, 3072, 1024, 1024, 12);
  attn_kernel<<<8192, 256, 0, stream>>>(qkvb, mask, aob);
  gemmc_kernel<128, false, false, false><<<dim3(32 * 8), 512, 0, stream>>>(
      aob, WoT, bo, ao2, nullptr, 8192, 1024, 1024, 1024, 8);
  ln_kernel<<<8192, 256, 0, stream>>>(ao2, nullptr, x, g1, beta1, h_f, h_b);
  gemmc_kernel<256, false, true, true><<<dim3(32 * 16), 512, 0, stream>>>(
      h_b, W1T, bf1, ff1, nullptr, 8192, 4096, 1024, 1024, 16);
  gemmc_kernel<256, true, false, false><<<dim3(32 * 8), 512, 0, stream>>>(
      ff1, W2T, bf2, ff2, ff2p2, 8192, 1024, 4096, 2048, 4);
  ln_kernel<<<8192, 256, 0, stream>>>(ff2, ff2p2, h_f, g2, beta2, out, nullptr);
}